// Round 6
// baseline (1389.598 us; speedup 1.0000x reference)
//
#include <hip/hip_runtime.h>

#define HDIM 2048
#define HH (HDIM * HDIM)          // 4,194,304
#define NIDX 2000000
#define BINS 256
#define NCOPY 16
#define TL_BLOCKS 2048            // tabloss grid (partials count)
#define NBKT 64                   // buckets (by pixel>>16): 64KB f32 region/channel
#define NSEG 8                    // writer classes (blockIdx%8 ~ XCD)
#define SEGCAP 4608               // mean 3906 + 11 sd
#define SPLIT_BLOCKS 1024
#define GH_BLOCKS 2048            // 8 classes x 256 slices

// workspace layout (bytes)
#define PART_OFF   0                        // double partials[2048] = 16 KB
#define TAB_OFF    16384                    // float tab[3*BINS] = 3 KB
#define CUR_OFF    20480                    // uint cur_d[512] + cur_r[512] = 4 KB
#define HIST_OFF   24576                    // uint hist[16][6][256] = 96 KB
#define FLAGS_OFF  131072                   // uchar flags[HH] = 4 MB
#define SORT_D_OFF 4325376                  // ushort sd[512][SEGCAP] = 4.5 MB
#define SORT_R_OFF 9043968                  // ushort sr[512][SEGCAP] = 4.5 MB (ends 13.1 MB)
#define MEMSET_BYTES (4325376 - 20480)      // cur + hist + pad + flags

// Node 1: bucket-split the sample indices. Entry = low 16 bits (bucket is
// high 6). Segment (bucket, class) is appended only by blocks of one class
// (blockIdx%8 ~ XCD round-robin) -> append-stream lines stay in one L2.
// Cursor atomics: 4M ops on 4KB hot region (R3 evidence: hot atomics merge).
__global__ __launch_bounds__(256) void split_kernel(
    const int* __restrict__ i0, const int* __restrict__ i1,
    const int* __restrict__ i2, const int* __restrict__ i3,
    unsigned* __restrict__ cur_d, unsigned* __restrict__ cur_r,
    unsigned short* __restrict__ sd, unsigned short* __restrict__ sr)
{
    const int w = blockIdx.x & (NSEG - 1);
    const int stride = gridDim.x * 256;
    for (int q = blockIdx.x * 256 + threadIdx.x; q < NIDX / 4; q += stride) {
        const int4 a = ((const int4*)i0)[q];
        const int4 b = ((const int4*)i1)[q];
        const int4 c = ((const int4*)i2)[q];
        const int4 d = ((const int4*)i3)[q];
        const int pd[4] = {a.x * HDIM + b.x, a.y * HDIM + b.y, a.z * HDIM + b.z, a.w * HDIM + b.w};
        const int pr[4] = {c.x * HDIM + d.x, c.y * HDIM + d.y, c.z * HDIM + d.z, c.w * HDIM + d.w};
#pragma unroll
        for (int k = 0; k < 4; k++) {
            const int segd = ((pd[k] >> 16) * NSEG) + w;
            const unsigned posd = atomicAdd(&cur_d[segd], 1u);
            if (posd < SEGCAP) sd[segd * SEGCAP + posd] = (unsigned short)(pd[k] & 0xFFFF);
            const int segr = ((pr[k] >> 16) * NSEG) + w;
            const unsigned posr = atomicAdd(&cur_r[segr], 1u);
            if (posr < SEGCAP) sr[segr * SEGCAP + posr] = (unsigned short)(pr[k] & 0xFFFF);
        }
    }
}

// Node 2: bucketed gather-histogram directly from ref/tgt/masks (no packed
// arrays). Block (class x = blockIdx%8, slice = blockIdx/8) sweeps its
// class's 8 buckets IN ORDER -> per class ~1-2 live regions (~1MB) -> gathers
// are L2 hits instead of 2.8TB/s random-line misses (R5 counter evidence).
// Bin math identical to validated pack. Bin-0 in registers. Flags = 1-byte
// idempotent stores, L2-local per bucket. Flush = 16-copy burst atomics.
__global__ __launch_bounds__(256) void ghist_kernel(
    const float* __restrict__ ref, const float* __restrict__ tgt,
    const float* __restrict__ msrc, const float* __restrict__ mtar,
    const unsigned* __restrict__ cur_d, const unsigned* __restrict__ cur_r,
    const unsigned short* __restrict__ sd, const unsigned short* __restrict__ sr,
    unsigned char* __restrict__ flags, unsigned* __restrict__ hist)
{
    __shared__ unsigned lhist[6 * BINS];
    for (int k = threadIdx.x; k < 6 * BINS; k += 256) lhist[k] = 0;
    __syncthreads();

    unsigned z[6] = {0, 0, 0, 0, 0, 0};
    const int x     = blockIdx.x & 7;
    const int slice = blockIdx.x >> 3;     // 0..255

    for (int m = 0; m < NBKT / 8; m++) {
        const int bkt  = x + 8 * m;
        const int base = bkt << 16;
        // ---- d side (ref, msrc): channels 0..2, writes flags ----
        for (int w = 0; w < NSEG; w++) {
            const int seg = bkt * NSEG + w;
            const unsigned lenu = cur_d[seg];
            const int len = (int)(lenu < SEGCAP ? lenu : SEGCAP);
            const int s0 = (slice * len) >> 8, s1 = ((slice + 1) * len) >> 8;
            const unsigned short* p = sd + seg * SEGCAP;
            for (int e = s0 + threadIdx.x; e < s1; e += 256) {
                const int pd = base | p[e];
                const float mm = msrc[pd];
                const float v0 = ref[pd], v1 = ref[HH + pd], v2 = ref[2 * HH + pd];
                flags[pd] = 1;
                const float f0 = ((v0 + 1.0f) * 0.5f) * 255.0f * mm;
                const float f1 = ((v1 + 1.0f) * 0.5f) * 255.0f * mm;
                const float f2 = ((v2 + 1.0f) * 0.5f) * 255.0f * mm;
                const unsigned b0 = (unsigned)(int)fminf(fmaxf(floorf(f0), 0.0f), 255.0f);
                const unsigned b1 = (unsigned)(int)fminf(fmaxf(floorf(f1), 0.0f), 255.0f);
                const unsigned b2 = (unsigned)(int)fminf(fmaxf(floorf(f2), 0.0f), 255.0f);
                if (b0) atomicAdd(&lhist[           b0], 1u); else z[0]++;
                if (b1) atomicAdd(&lhist[1 * BINS + b1], 1u); else z[1]++;
                if (b2) atomicAdd(&lhist[2 * BINS + b2], 1u); else z[2]++;
            }
        }
        // ---- r side (tgt, mtar): channels 3..5 ----
        for (int w = 0; w < NSEG; w++) {
            const int seg = bkt * NSEG + w;
            const unsigned lenu = cur_r[seg];
            const int len = (int)(lenu < SEGCAP ? lenu : SEGCAP);
            const int s0 = (slice * len) >> 8, s1 = ((slice + 1) * len) >> 8;
            const unsigned short* p = sr + seg * SEGCAP;
            for (int e = s0 + threadIdx.x; e < s1; e += 256) {
                const int pr = base | p[e];
                const float mm = mtar[pr];
                const float v0 = tgt[pr], v1 = tgt[HH + pr], v2 = tgt[2 * HH + pr];
                const float f0 = ((v0 + 1.0f) * 0.5f) * 255.0f * mm;
                const float f1 = ((v1 + 1.0f) * 0.5f) * 255.0f * mm;
                const float f2 = ((v2 + 1.0f) * 0.5f) * 255.0f * mm;
                const unsigned b0 = (unsigned)(int)fminf(fmaxf(floorf(f0), 0.0f), 255.0f);
                const unsigned b1 = (unsigned)(int)fminf(fmaxf(floorf(f1), 0.0f), 255.0f);
                const unsigned b2 = (unsigned)(int)fminf(fmaxf(floorf(f2), 0.0f), 255.0f);
                if (b0) atomicAdd(&lhist[3 * BINS + b0], 1u); else z[3]++;
                if (b1) atomicAdd(&lhist[4 * BINS + b1], 1u); else z[4]++;
                if (b2) atomicAdd(&lhist[5 * BINS + b2], 1u); else z[5]++;
            }
        }
    }
#pragma unroll
    for (int c = 0; c < 6; c++)
        if (z[c]) atomicAdd(&lhist[c * BINS], z[c]);
    __syncthreads();
    unsigned* h = hist + (blockIdx.x & (NCOPY - 1)) * (6 * BINS);
    for (int k = threadIdx.x; k < 6 * BINS; k += 256) {
        const unsigned v = lhist[k];
        if (v) atomicAdd(&h[k], v);
    }
}

// Node 3: transfer table computed ONCE (1 block). Validated logic: exact int
// scan -> single-rounding divide -> bsearch. Sums the 16 hist copies.
__global__ __launch_bounds__(256) void table_kernel(
    const unsigned* __restrict__ hist, float* __restrict__ tabg)
{
    __shared__ float    cdf[6 * BINS];
    __shared__ unsigned wsum[4];

    const int t    = threadIdx.x;
    const int lane = t & 63;
    const int wid  = t >> 6;

    for (int ch = 0; ch < 6; ch++) {
        unsigned x = 0;
#pragma unroll
        for (int cp = 0; cp < NCOPY; cp++) x += hist[cp * (6 * BINS) + ch * BINS + t];
#pragma unroll
        for (int d = 1; d < 64; d <<= 1) {
            const unsigned y = __shfl_up(x, d, 64);
            if (lane >= d) x += y;
        }
        if (lane == 63) wsum[wid] = x;
        __syncthreads();
        unsigned prefix = 0;
        for (int w = 0; w < wid; w++) prefix += wsum[w];
        x += prefix;
        cdf[ch * BINS + t] = (float)x / 2000000.0f;   // exact int < 2^24, single rounding
        __syncthreads();
    }
    for (int c = 0; c < 3; c++) {
        float o;
        if (t == 0)             o = 0.0f;
        else if (t == BINS - 1) o = 255.0f;
        else {
            const float v = cdf[c * BINS + t];
            const float* arr = cdf + (3 + c) * BINS;
            int lo = 0, hi = 256;   // lower_bound: first k with arr[k] >= v
            while (lo < hi) { const int mid = (lo + hi) >> 1; if (arr[mid] < v) lo = mid + 1; else hi = mid; }
            const int J0 = ((lo > 1) ? lo : 1) - 1;
            int lo2 = 0, hi2 = 256; // upper_bound: first k with arr[k] > v
            while (lo2 < hi2) { const int mid = (lo2 + hi2) >> 1; if (arr[mid] <= v) lo2 = mid + 1; else hi2 = mid; }
            const int J1 = ((lo2 - 1) < 254 ? (lo2 - 1) : 254);
            const bool found = (lo2 >= 1) && (J0 <= J1);
            o = found ? (float)(J0 + 1) : (float)t;
        }
        tabg[c * BINS + t] = o;
    }
}

// Node 4: streaming loss. Sampled flag from the 4MB byte array (coalesced
// uchar4 loads). Plain per-block partial store; stream-order visibility.
__global__ __launch_bounds__(256) void tabloss_kernel(
    const float* __restrict__ inp, const float* __restrict__ ref,
    const float* __restrict__ msrc, const float* __restrict__ tabg,
    const unsigned char* __restrict__ flags, double* __restrict__ partials)
{
    __shared__ float  tab[3 * BINS];
    __shared__ double red[256];

    const int t = threadIdx.x;
    for (int k = t; k < 3 * BINS; k += 256) tab[k] = tabg[k];
    __syncthreads();

    double local = 0.0;
    const int stride = gridDim.x * 256;
    for (int g = blockIdx.x * 256 + t; g < HH / 4; g += stride) {
        const int p = g * 4;
        const float4 mv = *(const float4*)(msrc + p);
        const uchar4 fw = *(const uchar4*)(flags + p);
        const unsigned samp[4] = {fw.x, fw.y, fw.z, fw.w};
        const float m[4] = {mv.x, mv.y, mv.z, mv.w};
#pragma unroll
        for (int c = 0; c < 3; c++) {
            const float4 rv = *(const float4*)(ref + c * HH + p);
            const float4 iv = *(const float4*)(inp + c * HH + p);
            const float r[4] = {rv.x, rv.y, rv.z, rv.w};
            const float x4[4] = {iv.x, iv.y, iv.z, iv.w};
            float s = 0.0f;
#pragma unroll
            for (int k = 0; k < 4; k++) {
                const float mm = m[k];
                const float refm = ((r[k] + 1.0f) * 0.5f) * 255.0f * mm;   // ref_masked
                const float inpm = ((x4[k] + 1.0f) * 0.5f) * 255.0f * mm;  // input_masked
                float matchv;
                if (samp[k]) {
                    const int bidx = (int)fminf(fmaxf(refm, 0.0f), 255.0f); // clip-then-trunc
                    matchv = tab[c * BINS + bidx];
                } else {
                    matchv = refm;
                }
                const float dd = inpm - matchv * mm;
                s += dd * dd;
            }
            local += (double)s;
        }
    }
    red[t] = local;
    __syncthreads();
    for (int s2 = 128; s2 > 0; s2 >>= 1) {
        if (t < s2) red[t] += red[t + s2];
        __syncthreads();
    }
    if (t == 0) partials[blockIdx.x] = red[0];
}

// Node 5: single-block finalize (plain loads; stream order guarantees visibility).
__global__ __launch_bounds__(256) void finalize_kernel(
    const double* __restrict__ partials, float* __restrict__ out)
{
    const int t = threadIdx.x;
    double s = 0.0;
    for (int k = t; k < TL_BLOCKS; k += 256) s += partials[k];
    __shared__ double red[256];
    red[t] = s;
    __syncthreads();
    for (int s2 = 128; s2 > 0; s2 >>= 1) {
        if (t < s2) red[t] += red[t + s2];
        __syncthreads();
    }
    if (t == 0) out[0] = (float)(red[0] / (double)(3 * HH));
}

extern "C" void kernel_launch(void* const* d_in, const int* in_sizes, int n_in,
                              void* d_out, int out_size, void* d_ws, size_t ws_size,
                              hipStream_t stream)
{
    const float* input_data  = (const float*)d_in[0];
    const float* target_data = (const float*)d_in[1];
    const float* mask_src    = (const float*)d_in[2];
    const float* mask_tar    = (const float*)d_in[3];
    const int*   i0          = (const int*)d_in[4];
    const int*   i1          = (const int*)d_in[5];
    const int*   i2          = (const int*)d_in[6];
    const int*   i3          = (const int*)d_in[7];
    const float* ref_data    = (const float*)d_in[8];
    float* out = (float*)d_out;

    char* ws = (char*)d_ws;
    double*         partials = (double*)(ws + PART_OFF);
    float*          tabg     = (float*)(ws + TAB_OFF);
    unsigned*       cur_d    = (unsigned*)(ws + CUR_OFF);
    unsigned*       cur_r    = (unsigned*)(ws + CUR_OFF + 2048);
    unsigned*       hist     = (unsigned*)(ws + HIST_OFF);
    unsigned char*  flags    = (unsigned char*)(ws + FLAGS_OFF);
    unsigned short* sd       = (unsigned short*)(ws + SORT_D_OFF);
    unsigned short* sr       = (unsigned short*)(ws + SORT_R_OFF);

    hipMemsetAsync(ws + CUR_OFF, 0, MEMSET_BYTES, stream);
    split_kernel<<<SPLIT_BLOCKS, 256, 0, stream>>>(i0, i1, i2, i3, cur_d, cur_r, sd, sr);
    ghist_kernel<<<GH_BLOCKS, 256, 0, stream>>>(ref_data, target_data, mask_src, mask_tar,
                                                cur_d, cur_r, sd, sr, flags, hist);
    table_kernel<<<1, 256, 0, stream>>>(hist, tabg);
    tabloss_kernel<<<TL_BLOCKS, 256, 0, stream>>>(input_data, ref_data, mask_src, tabg,
                                                  flags, partials);
    finalize_kernel<<<1, 256, 0, stream>>>(partials, out);
}

// Round 7
// 371.711 us; speedup vs baseline: 3.7384x; 3.7384x over previous
//
#include <hip/hip_runtime.h>

#define HDIM 2048
#define HH (HDIM * HDIM)          // 4,194,304
#define NIDX 2000000
#define BINS 256
#define NCOPY 16
#define TL_BLOCKS 2048            // tabloss grid (partials count)
#define WH_BLOCKS 2048
#define NWIN 8                    // address windows: pd>>19, 2MB packed bytes each

// workspace layout (bytes) — proven 33 MiB R3/R5 layout
#define PART_OFF     0                      // double partials[TL_BLOCKS] = 16 KB
#define TAB_OFF      16384                  // float tab[3*BINS] = 3 KB
#define HIST_OFF     20480                  // uint hist[NCOPY][6][256] = 96 KB
#define PACKED_D_OFF 1048576                // uint packed_d[HH] = 16 MB (byte3 = sampled flag)
#define PACKED_R_OFF 17825792               // uint packed_r[HH] = 16 MB

// Node 1: zero hist + pack 3 channel bins (mask folded: v*0 -> bin 0)
// into bits 0..23 of one uint per pixel. Byte 3 left ZERO (sampled flag).
__global__ __launch_bounds__(256) void pack_kernel(
    const float* __restrict__ ref, const float* __restrict__ tgt,
    const float* __restrict__ msrc, const float* __restrict__ mtar,
    unsigned* __restrict__ packed_d, unsigned* __restrict__ packed_r,
    unsigned* __restrict__ hist)
{
    const int gtid = blockIdx.x * 256 + threadIdx.x;
    const int stride = gridDim.x * 256;

    for (int k = gtid; k < NCOPY * 6 * BINS; k += stride) hist[k] = 0;

    for (int g = gtid; g < HH / 4; g += stride) {
        const int p = g * 4;
        const float4 ms4 = *(const float4*)(msrc + p);
        const float4 mt4 = *(const float4*)(mtar + p);
        const float ms[4] = {ms4.x, ms4.y, ms4.z, ms4.w};
        const float mt[4] = {mt4.x, mt4.y, mt4.z, mt4.w};
        unsigned od[4] = {0, 0, 0, 0}, orr[4] = {0, 0, 0, 0};
#pragma unroll
        for (int c = 0; c < 3; c++) {
            const float4 rv = *(const float4*)(ref + c * HH + p);
            const float4 tv = *(const float4*)(tgt + c * HH + p);
            const float r[4] = {rv.x, rv.y, rv.z, rv.w};
            const float tt[4] = {tv.x, tv.y, tv.z, tv.w};
#pragma unroll
            for (int k = 0; k < 4; k++) {
                // reference op order: ((x+1)*0.5)*255, then * mask
                const float vd = ((r[k] + 1.0f) * 0.5f) * 255.0f * ms[k];
                const float vr = ((tt[k] + 1.0f) * 0.5f) * 255.0f * mt[k];
                const unsigned bd = (unsigned)(int)fminf(fmaxf(floorf(vd), 0.0f), 255.0f);
                const unsigned br = (unsigned)(int)fminf(fmaxf(floorf(vr), 0.0f), 255.0f);
                od[k]  |= bd << (8 * c);
                orr[k] |= br << (8 * c);
            }
        }
        *(uint4*)(packed_d + p) = make_uint4(od[0], od[1], od[2], od[3]);
        *(uint4*)(packed_r + p) = make_uint4(orr[0], orr[1], orr[2], orr[3]);
    }
}

// Node 2: WINDOWED gather histogram. R7: the random gather over 32 MB runs at
// the memory system's random-line service rate (2.8 TB/s, R3/R5 measured,
// occupancy-independent). Instead: 8 address-windows per side (2 MB of packed
// bytes each, L2-resident per XCD); each pass streams the index arrays
// (sequential, ~6 TB/s) and gathers only in-window pixels -> gathers become
// L2 hits. No atomic allocators (R6 lesson), no capacity hazards.
// Sampled flag = byte3 plain store into the gathered (resident) line
// (R5-proven benign race). Bin-0 in registers; 16-copy burst flush.
__global__ __launch_bounds__(256) void whist_kernel(
    unsigned* __restrict__ packed_d, const unsigned* __restrict__ packed_r,
    const int* __restrict__ i0, const int* __restrict__ i1,
    const int* __restrict__ i2, const int* __restrict__ i3,
    unsigned* __restrict__ hist)
{
    __shared__ unsigned lhist[6 * BINS];
    for (int k = threadIdx.x; k < 6 * BINS; k += 256) lhist[k] = 0;
    __syncthreads();

    unsigned z0 = 0, z1 = 0, z2 = 0, z3 = 0, z4 = 0, z5 = 0;
    unsigned char* sampled = (unsigned char*)packed_d;
    const int stride = gridDim.x * 256;

    // ---- d side: ref-image histogram + sampled flags ----
    for (int w = 0; w < NWIN; w++) {
        for (int q = blockIdx.x * 256 + threadIdx.x; q < NIDX / 4; q += stride) {
            const int4 a = ((const int4*)i0)[q];
            const int4 b = ((const int4*)i1)[q];
            const int pd[4] = {a.x * HDIM + b.x, a.y * HDIM + b.y,
                               a.z * HDIM + b.z, a.w * HDIM + b.w};
#pragma unroll
            for (int k = 0; k < 4; k++) {
                if ((pd[k] >> 19) == w) {
                    const unsigned wd = packed_d[pd[k]];
                    sampled[pd[k] * 4 + 3] = 1;      // in-window line, benign race
                    const unsigned d0 =  wd        & 255u;
                    const unsigned d1 = (wd >> 8 ) & 255u;
                    const unsigned d2 = (wd >> 16) & 255u;
                    if (d0) atomicAdd(&lhist[           d0], 1u); else z0++;
                    if (d1) atomicAdd(&lhist[1 * BINS + d1], 1u); else z1++;
                    if (d2) atomicAdd(&lhist[2 * BINS + d2], 1u); else z2++;
                }
            }
        }
    }
    // ---- r side: target-image histogram ----
    for (int w = 0; w < NWIN; w++) {
        for (int q = blockIdx.x * 256 + threadIdx.x; q < NIDX / 4; q += stride) {
            const int4 c = ((const int4*)i2)[q];
            const int4 d = ((const int4*)i3)[q];
            const int pr[4] = {c.x * HDIM + d.x, c.y * HDIM + d.y,
                               c.z * HDIM + d.z, c.w * HDIM + d.w};
#pragma unroll
            for (int k = 0; k < 4; k++) {
                if ((pr[k] >> 19) == w) {
                    const unsigned wr = packed_r[pr[k]];
                    const unsigned r0 =  wr        & 255u;
                    const unsigned r1 = (wr >> 8 ) & 255u;
                    const unsigned r2 = (wr >> 16) & 255u;
                    if (r0) atomicAdd(&lhist[3 * BINS + r0], 1u); else z3++;
                    if (r1) atomicAdd(&lhist[4 * BINS + r1], 1u); else z4++;
                    if (r2) atomicAdd(&lhist[5 * BINS + r2], 1u); else z5++;
                }
            }
        }
    }

    if (z0) atomicAdd(&lhist[0 * BINS], z0);
    if (z1) atomicAdd(&lhist[1 * BINS], z1);
    if (z2) atomicAdd(&lhist[2 * BINS], z2);
    if (z3) atomicAdd(&lhist[3 * BINS], z3);
    if (z4) atomicAdd(&lhist[4 * BINS], z4);
    if (z5) atomicAdd(&lhist[5 * BINS], z5);
    __syncthreads();
    unsigned* h = hist + (blockIdx.x & (NCOPY - 1)) * (6 * BINS);
    for (int k = threadIdx.x; k < 6 * BINS; k += 256) {
        const unsigned v = lhist[k];
        if (v) atomicAdd(&h[k], v);
    }
}

// Node 3: transfer table computed ONCE (1 block). Validated logic: exact int
// scan -> single-rounding divide -> bsearch. Sums the 16 hist copies.
__global__ __launch_bounds__(256) void table_kernel(
    const unsigned* __restrict__ hist, float* __restrict__ tabg)
{
    __shared__ float    cdf[6 * BINS];
    __shared__ unsigned wsum[4];

    const int t    = threadIdx.x;
    const int lane = t & 63;
    const int wid  = t >> 6;

    for (int ch = 0; ch < 6; ch++) {
        unsigned x = 0;
#pragma unroll
        for (int cp = 0; cp < NCOPY; cp++) x += hist[cp * (6 * BINS) + ch * BINS + t];
#pragma unroll
        for (int d = 1; d < 64; d <<= 1) {
            const unsigned y = __shfl_up(x, d, 64);
            if (lane >= d) x += y;
        }
        if (lane == 63) wsum[wid] = x;
        __syncthreads();
        unsigned prefix = 0;
        for (int w = 0; w < wid; w++) prefix += wsum[w];
        x += prefix;
        cdf[ch * BINS + t] = (float)x / 2000000.0f;   // exact int < 2^24, single rounding
        __syncthreads();
    }
    for (int c = 0; c < 3; c++) {
        float o;
        if (t == 0)             o = 0.0f;
        else if (t == BINS - 1) o = 255.0f;
        else {
            const float v = cdf[c * BINS + t];
            const float* arr = cdf + (3 + c) * BINS;
            int lo = 0, hi = 256;   // lower_bound: first k with arr[k] >= v
            while (lo < hi) { const int mid = (lo + hi) >> 1; if (arr[mid] < v) lo = mid + 1; else hi = mid; }
            const int J0 = ((lo > 1) ? lo : 1) - 1;
            int lo2 = 0, hi2 = 256; // upper_bound: first k with arr[k] > v
            while (lo2 < hi2) { const int mid = (lo2 + hi2) >> 1; if (arr[mid] <= v) lo2 = mid + 1; else hi2 = mid; }
            const int J1 = ((lo2 - 1) < 254 ? (lo2 - 1) : 254);
            const bool found = (lo2 >= 1) && (J0 <= J1);
            o = found ? (float)(J0 + 1) : (float)t;
        }
        tabg[c * BINS + t] = o;
    }
}

// Node 4: streaming loss. Sampled flag read from packed_d byte 3 (coalesced
// uint4 loads). Plain per-block partial store; stream-order visibility.
__global__ __launch_bounds__(256) void tabloss_kernel(
    const float* __restrict__ inp, const float* __restrict__ ref,
    const float* __restrict__ msrc, const float* __restrict__ tabg,
    const unsigned* __restrict__ packed_d, double* __restrict__ partials)
{
    __shared__ float  tab[3 * BINS];
    __shared__ double red[256];

    const int t = threadIdx.x;
    for (int k = t; k < 3 * BINS; k += 256) tab[k] = tabg[k];
    __syncthreads();

    double local = 0.0;
    const int stride = gridDim.x * 256;
    for (int g = blockIdx.x * 256 + t; g < HH / 4; g += stride) {
        const int p = g * 4;
        const float4 mv = *(const float4*)(msrc + p);
        const uint4 pw = *(const uint4*)(packed_d + p);
        const unsigned samp[4] = {pw.x >> 24, pw.y >> 24, pw.z >> 24, pw.w >> 24};
        const float m[4] = {mv.x, mv.y, mv.z, mv.w};
#pragma unroll
        for (int c = 0; c < 3; c++) {
            const float4 rv = *(const float4*)(ref + c * HH + p);
            const float4 iv = *(const float4*)(inp + c * HH + p);
            const float r[4] = {rv.x, rv.y, rv.z, rv.w};
            const float x4[4] = {iv.x, iv.y, iv.z, iv.w};
            float s = 0.0f;
#pragma unroll
            for (int k = 0; k < 4; k++) {
                const float mm = m[k];
                const float refm = ((r[k] + 1.0f) * 0.5f) * 255.0f * mm;   // ref_masked
                const float inpm = ((x4[k] + 1.0f) * 0.5f) * 255.0f * mm;  // input_masked
                float matchv;
                if (samp[k]) {
                    const int bidx = (int)fminf(fmaxf(refm, 0.0f), 255.0f); // clip-then-trunc
                    matchv = tab[c * BINS + bidx];
                } else {
                    matchv = refm;
                }
                const float dd = inpm - matchv * mm;
                s += dd * dd;
            }
            local += (double)s;
        }
    }
    red[t] = local;
    __syncthreads();
    for (int s2 = 128; s2 > 0; s2 >>= 1) {
        if (t < s2) red[t] += red[t + s2];
        __syncthreads();
    }
    if (t == 0) partials[blockIdx.x] = red[0];
}

// Node 5: single-block finalize (plain loads; stream order guarantees visibility).
__global__ __launch_bounds__(256) void finalize_kernel(
    const double* __restrict__ partials, float* __restrict__ out)
{
    const int t = threadIdx.x;
    double s = 0.0;
    for (int k = t; k < TL_BLOCKS; k += 256) s += partials[k];
    __shared__ double red[256];
    red[t] = s;
    __syncthreads();
    for (int s2 = 128; s2 > 0; s2 >>= 1) {
        if (t < s2) red[t] += red[t + s2];
        __syncthreads();
    }
    if (t == 0) out[0] = (float)(red[0] / (double)(3 * HH));
}

extern "C" void kernel_launch(void* const* d_in, const int* in_sizes, int n_in,
                              void* d_out, int out_size, void* d_ws, size_t ws_size,
                              hipStream_t stream)
{
    const float* input_data  = (const float*)d_in[0];
    const float* target_data = (const float*)d_in[1];
    const float* mask_src    = (const float*)d_in[2];
    const float* mask_tar    = (const float*)d_in[3];
    const int*   i0          = (const int*)d_in[4];
    const int*   i1          = (const int*)d_in[5];
    const int*   i2          = (const int*)d_in[6];
    const int*   i3          = (const int*)d_in[7];
    const float* ref_data    = (const float*)d_in[8];
    float* out = (float*)d_out;

    char* ws = (char*)d_ws;
    double*   partials = (double*)(ws + PART_OFF);
    float*    tabg     = (float*)(ws + TAB_OFF);
    unsigned* hist     = (unsigned*)(ws + HIST_OFF);
    unsigned* packed_d = (unsigned*)(ws + PACKED_D_OFF);
    unsigned* packed_r = (unsigned*)(ws + PACKED_R_OFF);

    pack_kernel<<<2048, 256, 0, stream>>>(ref_data, target_data, mask_src, mask_tar,
                                          packed_d, packed_r, hist);
    whist_kernel<<<WH_BLOCKS, 256, 0, stream>>>(packed_d, packed_r, i0, i1, i2, i3, hist);
    table_kernel<<<1, 256, 0, stream>>>(hist, tabg);
    tabloss_kernel<<<TL_BLOCKS, 256, 0, stream>>>(input_data, ref_data, mask_src, tabg,
                                                  packed_d, partials);
    finalize_kernel<<<1, 256, 0, stream>>>(partials, out);
}

// Round 8
// 334.841 us; speedup vs baseline: 4.1500x; 1.1101x over previous
//
#include <hip/hip_runtime.h>

#define HDIM 2048
#define HH (HDIM * HDIM)          // 4,194,304
#define NIDX 2000000
#define BINS 256
#define NCOPY 16
#define TL_BLOCKS 2048            // tabloss grid (partials count)
#define WH_BLOCKS 2048
#define NWIN 8                    // address windows: pd>>19, 2MB packed bytes each

// workspace layout (bytes) — ~52.1 MB
#define PART_OFF     0                      // double partials[TL_BLOCKS] = 16 KB
#define TAB_OFF      16384                  // float tab[3*BINS] = 3 KB
#define HIST_OFF     20480                  // uint hist[NCOPY][6][256] = 96 KB
#define FLAGS_OFF    131072                 // uchar flags[HH] = 4 MB
#define PD_OFF       4325376                // int pd[NIDX] = 8 MB
#define PR_OFF       12713984               // int pr[NIDX] = 8 MB
#define PACKED_D_OFF 21102592               // uint packed_d[HH] = 16 MB
#define PACKED_R_OFF 37879808               // uint packed_r[HH] = 16 MB (ends ~52.1 MB)

// Node 1: zero hist/flags + pack 3 channel bins (mask folded: v*0 -> bin 0)
// into bits 0..23 of one uint per pixel + flatten sample indices to pd/pr
// (R8: so whist's 8 window passes restream 8MB instead of 16MB per side).
__global__ __launch_bounds__(256) void pack_kernel(
    const float* __restrict__ ref, const float* __restrict__ tgt,
    const float* __restrict__ msrc, const float* __restrict__ mtar,
    const int* __restrict__ i0, const int* __restrict__ i1,
    const int* __restrict__ i2, const int* __restrict__ i3,
    unsigned* __restrict__ packed_d, unsigned* __restrict__ packed_r,
    int* __restrict__ pdArr, int* __restrict__ prArr,
    unsigned* __restrict__ hist, unsigned* __restrict__ flags32)
{
    const int gtid = blockIdx.x * 256 + threadIdx.x;
    const int stride = gridDim.x * 256;

    for (int k = gtid; k < NCOPY * 6 * BINS; k += stride) hist[k] = 0;
    for (int k = gtid; k < HH / 4; k += stride) flags32[k] = 0;

    // flatten indices (streaming): pd = i0*2048 + i1, pr = i2*2048 + i3
    for (int s = gtid; s < NIDX / 4; s += stride) {
        const int4 a = ((const int4*)i0)[s];
        const int4 b = ((const int4*)i1)[s];
        const int4 c = ((const int4*)i2)[s];
        const int4 d = ((const int4*)i3)[s];
        ((int4*)pdArr)[s] = make_int4(a.x * HDIM + b.x, a.y * HDIM + b.y,
                                      a.z * HDIM + b.z, a.w * HDIM + b.w);
        ((int4*)prArr)[s] = make_int4(c.x * HDIM + d.x, c.y * HDIM + d.y,
                                      c.z * HDIM + d.z, c.w * HDIM + d.w);
    }

    for (int g = gtid; g < HH / 4; g += stride) {
        const int p = g * 4;
        const float4 ms4 = *(const float4*)(msrc + p);
        const float4 mt4 = *(const float4*)(mtar + p);
        const float ms[4] = {ms4.x, ms4.y, ms4.z, ms4.w};
        const float mt[4] = {mt4.x, mt4.y, mt4.z, mt4.w};
        unsigned od[4] = {0, 0, 0, 0}, orr[4] = {0, 0, 0, 0};
#pragma unroll
        for (int c = 0; c < 3; c++) {
            const float4 rv = *(const float4*)(ref + c * HH + p);
            const float4 tv = *(const float4*)(tgt + c * HH + p);
            const float r[4] = {rv.x, rv.y, rv.z, rv.w};
            const float tt[4] = {tv.x, tv.y, tv.z, tv.w};
#pragma unroll
            for (int k = 0; k < 4; k++) {
                // reference op order: ((x+1)*0.5)*255, then * mask
                const float vd = ((r[k] + 1.0f) * 0.5f) * 255.0f * ms[k];
                const float vr = ((tt[k] + 1.0f) * 0.5f) * 255.0f * mt[k];
                const unsigned bd = (unsigned)(int)fminf(fmaxf(floorf(vd), 0.0f), 255.0f);
                const unsigned br = (unsigned)(int)fminf(fmaxf(floorf(vr), 0.0f), 255.0f);
                od[k]  |= bd << (8 * c);
                orr[k] |= br << (8 * c);
            }
        }
        *(uint4*)(packed_d + p) = make_uint4(od[0], od[1], od[2], od[3]);
        *(uint4*)(packed_r + p) = make_uint4(orr[0], orr[1], orr[2], orr[3]);
    }
}

// Node 2: WINDOWED gather histogram (R7-proven locality: gather FETCH ~0;
// all gathers hit L2-resident 2MB windows). R8: index restream halved via
// pre-flattened pd/pr (8MB per window-pass instead of 16MB). Flags go to a
// dedicated 4MB array (window-local, idempotent byte stores) instead of
// dirtying the 16MB packed_d. Bin-0 in registers; 16-copy burst flush.
__global__ __launch_bounds__(256) void whist_kernel(
    const unsigned* __restrict__ packed_d, const unsigned* __restrict__ packed_r,
    const int* __restrict__ pdArr, const int* __restrict__ prArr,
    unsigned char* __restrict__ flags, unsigned* __restrict__ hist)
{
    __shared__ unsigned lhist[6 * BINS];
    for (int k = threadIdx.x; k < 6 * BINS; k += 256) lhist[k] = 0;
    __syncthreads();

    unsigned z0 = 0, z1 = 0, z2 = 0, z3 = 0, z4 = 0, z5 = 0;
    const int stride = gridDim.x * 256;

    // ---- d side: ref-image histogram + sampled flags ----
    for (int w = 0; w < NWIN; w++) {
        for (int q = blockIdx.x * 256 + threadIdx.x; q < NIDX / 4; q += stride) {
            const int4 pv = ((const int4*)pdArr)[q];
            const int pd[4] = {pv.x, pv.y, pv.z, pv.w};
#pragma unroll
            for (int k = 0; k < 4; k++) {
                if ((pd[k] >> 19) == w) {
                    const unsigned wd = packed_d[pd[k]];
                    flags[pd[k]] = 1;                // in-window, benign idempotent race
                    const unsigned d0 =  wd        & 255u;
                    const unsigned d1 = (wd >> 8 ) & 255u;
                    const unsigned d2 = (wd >> 16) & 255u;
                    if (d0) atomicAdd(&lhist[           d0], 1u); else z0++;
                    if (d1) atomicAdd(&lhist[1 * BINS + d1], 1u); else z1++;
                    if (d2) atomicAdd(&lhist[2 * BINS + d2], 1u); else z2++;
                }
            }
        }
    }
    // ---- r side: target-image histogram ----
    for (int w = 0; w < NWIN; w++) {
        for (int q = blockIdx.x * 256 + threadIdx.x; q < NIDX / 4; q += stride) {
            const int4 pv = ((const int4*)prArr)[q];
            const int pr[4] = {pv.x, pv.y, pv.z, pv.w};
#pragma unroll
            for (int k = 0; k < 4; k++) {
                if ((pr[k] >> 19) == w) {
                    const unsigned wr = packed_r[pr[k]];
                    const unsigned r0 =  wr        & 255u;
                    const unsigned r1 = (wr >> 8 ) & 255u;
                    const unsigned r2 = (wr >> 16) & 255u;
                    if (r0) atomicAdd(&lhist[3 * BINS + r0], 1u); else z3++;
                    if (r1) atomicAdd(&lhist[4 * BINS + r1], 1u); else z4++;
                    if (r2) atomicAdd(&lhist[5 * BINS + r2], 1u); else z5++;
                }
            }
        }
    }

    if (z0) atomicAdd(&lhist[0 * BINS], z0);
    if (z1) atomicAdd(&lhist[1 * BINS], z1);
    if (z2) atomicAdd(&lhist[2 * BINS], z2);
    if (z3) atomicAdd(&lhist[3 * BINS], z3);
    if (z4) atomicAdd(&lhist[4 * BINS], z4);
    if (z5) atomicAdd(&lhist[5 * BINS], z5);
    __syncthreads();
    unsigned* h = hist + (blockIdx.x & (NCOPY - 1)) * (6 * BINS);
    for (int k = threadIdx.x; k < 6 * BINS; k += 256) {
        const unsigned v = lhist[k];
        if (v) atomicAdd(&h[k], v);
    }
}

// Node 3: transfer table computed ONCE (1 block). Validated logic: exact int
// scan -> single-rounding divide -> bsearch. Sums the 16 hist copies.
__global__ __launch_bounds__(256) void table_kernel(
    const unsigned* __restrict__ hist, float* __restrict__ tabg)
{
    __shared__ float    cdf[6 * BINS];
    __shared__ unsigned wsum[4];

    const int t    = threadIdx.x;
    const int lane = t & 63;
    const int wid  = t >> 6;

    for (int ch = 0; ch < 6; ch++) {
        unsigned x = 0;
#pragma unroll
        for (int cp = 0; cp < NCOPY; cp++) x += hist[cp * (6 * BINS) + ch * BINS + t];
#pragma unroll
        for (int d = 1; d < 64; d <<= 1) {
            const unsigned y = __shfl_up(x, d, 64);
            if (lane >= d) x += y;
        }
        if (lane == 63) wsum[wid] = x;
        __syncthreads();
        unsigned prefix = 0;
        for (int w = 0; w < wid; w++) prefix += wsum[w];
        x += prefix;
        cdf[ch * BINS + t] = (float)x / 2000000.0f;   // exact int < 2^24, single rounding
        __syncthreads();
    }
    for (int c = 0; c < 3; c++) {
        float o;
        if (t == 0)             o = 0.0f;
        else if (t == BINS - 1) o = 255.0f;
        else {
            const float v = cdf[c * BINS + t];
            const float* arr = cdf + (3 + c) * BINS;
            int lo = 0, hi = 256;   // lower_bound: first k with arr[k] >= v
            while (lo < hi) { const int mid = (lo + hi) >> 1; if (arr[mid] < v) lo = mid + 1; else hi = mid; }
            const int J0 = ((lo > 1) ? lo : 1) - 1;
            int lo2 = 0, hi2 = 256; // upper_bound: first k with arr[k] > v
            while (lo2 < hi2) { const int mid = (lo2 + hi2) >> 1; if (arr[mid] <= v) lo2 = mid + 1; else hi2 = mid; }
            const int J1 = ((lo2 - 1) < 254 ? (lo2 - 1) : 254);
            const bool found = (lo2 >= 1) && (J0 <= J1);
            o = found ? (float)(J0 + 1) : (float)t;
        }
        tabg[c * BINS + t] = o;
    }
}

// Node 4: streaming loss. Sampled flag from the 4MB byte array (coalesced
// uchar4 loads — 12MB less traffic than reading packed_d). Plain per-block
// partial store; stream-order visibility.
__global__ __launch_bounds__(256) void tabloss_kernel(
    const float* __restrict__ inp, const float* __restrict__ ref,
    const float* __restrict__ msrc, const float* __restrict__ tabg,
    const unsigned char* __restrict__ flags, double* __restrict__ partials)
{
    __shared__ float  tab[3 * BINS];
    __shared__ double red[256];

    const int t = threadIdx.x;
    for (int k = t; k < 3 * BINS; k += 256) tab[k] = tabg[k];
    __syncthreads();

    double local = 0.0;
    const int stride = gridDim.x * 256;
    for (int g = blockIdx.x * 256 + t; g < HH / 4; g += stride) {
        const int p = g * 4;
        const float4 mv = *(const float4*)(msrc + p);
        const uchar4 fw = *(const uchar4*)(flags + p);
        const unsigned samp[4] = {fw.x, fw.y, fw.z, fw.w};
        const float m[4] = {mv.x, mv.y, mv.z, mv.w};
#pragma unroll
        for (int c = 0; c < 3; c++) {
            const float4 rv = *(const float4*)(ref + c * HH + p);
            const float4 iv = *(const float4*)(inp + c * HH + p);
            const float r[4] = {rv.x, rv.y, rv.z, rv.w};
            const float x4[4] = {iv.x, iv.y, iv.z, iv.w};
            float s = 0.0f;
#pragma unroll
            for (int k = 0; k < 4; k++) {
                const float mm = m[k];
                const float refm = ((r[k] + 1.0f) * 0.5f) * 255.0f * mm;   // ref_masked
                const float inpm = ((x4[k] + 1.0f) * 0.5f) * 255.0f * mm;  // input_masked
                float matchv;
                if (samp[k]) {
                    const int bidx = (int)fminf(fmaxf(refm, 0.0f), 255.0f); // clip-then-trunc
                    matchv = tab[c * BINS + bidx];
                } else {
                    matchv = refm;
                }
                const float dd = inpm - matchv * mm;
                s += dd * dd;
            }
            local += (double)s;
        }
    }
    red[t] = local;
    __syncthreads();
    for (int s2 = 128; s2 > 0; s2 >>= 1) {
        if (t < s2) red[t] += red[t + s2];
        __syncthreads();
    }
    if (t == 0) partials[blockIdx.x] = red[0];
}

// Node 5: single-block finalize (plain loads; stream order guarantees visibility).
__global__ __launch_bounds__(256) void finalize_kernel(
    const double* __restrict__ partials, float* __restrict__ out)
{
    const int t = threadIdx.x;
    double s = 0.0;
    for (int k = t; k < TL_BLOCKS; k += 256) s += partials[k];
    __shared__ double red[256];
    red[t] = s;
    __syncthreads();
    for (int s2 = 128; s2 > 0; s2 >>= 1) {
        if (t < s2) red[t] += red[t + s2];
        __syncthreads();
    }
    if (t == 0) out[0] = (float)(red[0] / (double)(3 * HH));
}

extern "C" void kernel_launch(void* const* d_in, const int* in_sizes, int n_in,
                              void* d_out, int out_size, void* d_ws, size_t ws_size,
                              hipStream_t stream)
{
    const float* input_data  = (const float*)d_in[0];
    const float* target_data = (const float*)d_in[1];
    const float* mask_src    = (const float*)d_in[2];
    const float* mask_tar    = (const float*)d_in[3];
    const int*   i0          = (const int*)d_in[4];
    const int*   i1          = (const int*)d_in[5];
    const int*   i2          = (const int*)d_in[6];
    const int*   i3          = (const int*)d_in[7];
    const float* ref_data    = (const float*)d_in[8];
    float* out = (float*)d_out;

    char* ws = (char*)d_ws;
    double*        partials = (double*)(ws + PART_OFF);
    float*         tabg     = (float*)(ws + TAB_OFF);
    unsigned*      hist     = (unsigned*)(ws + HIST_OFF);
    unsigned*      flags32  = (unsigned*)(ws + FLAGS_OFF);
    unsigned char* flags    = (unsigned char*)(ws + FLAGS_OFF);
    int*           pdArr    = (int*)(ws + PD_OFF);
    int*           prArr    = (int*)(ws + PR_OFF);
    unsigned*      packed_d = (unsigned*)(ws + PACKED_D_OFF);
    unsigned*      packed_r = (unsigned*)(ws + PACKED_R_OFF);

    pack_kernel<<<2048, 256, 0, stream>>>(ref_data, target_data, mask_src, mask_tar,
                                          i0, i1, i2, i3,
                                          packed_d, packed_r, pdArr, prArr, hist, flags32);
    whist_kernel<<<WH_BLOCKS, 256, 0, stream>>>(packed_d, packed_r, pdArr, prArr,
                                                flags, hist);
    table_kernel<<<1, 256, 0, stream>>>(hist, tabg);
    tabloss_kernel<<<TL_BLOCKS, 256, 0, stream>>>(input_data, ref_data, mask_src, tabg,
                                                  flags, partials);
    finalize_kernel<<<1, 256, 0, stream>>>(partials, out);
}